// Round 2
// baseline (1163.626 us; speedup 1.0000x reference)
//
#include <hip/hip_runtime.h>

#define B_    2
#define N_    4096
#define E_    262144
#define EPN   64          // E_/N_ edges aggregated per node (reshape-sum)
#define F_    5
#define ED    150
#define ND    100
#define NIN   154         // 3 + ED + 1
#define EIN   9

typedef float f4 __attribute__((ext_vector_type(4)));

struct __align__(16) SM {
    float W2[152][160];    // 97280 B  eW2, rows/cols >=150 zero; stride 160 -> bank-clean b128
    float h[EPN][156];     // 39936 B  layer-1 outputs, stride 156 (16B-aligned rows, 2-way banks = free)
    float W1[EIN][152];    //  5472 B
    float b1[152];
    float b2[152];
    float red[4][152];     //  2432 B  cross-wave reduction
    float Ein[EPN][EIN];   //  2304 B
    float nin[NIN];
    float hA[ND];
    float hB[ND];
    float hC[ND];
};                          // ~150.5 KB total (< 160 KiB gfx950 LDS)

__global__ __launch_bounds__(256, 1)
void deltagn_fused(const float* __restrict__ V,
                   const float* __restrict__ dt,
                   const float* __restrict__ eW1,
                   const float* __restrict__ eb1,
                   const float* __restrict__ eW2,
                   const float* __restrict__ eb2,
                   const float* __restrict__ nW1,
                   const float* __restrict__ nb1,
                   const float* __restrict__ nW2,
                   const float* __restrict__ nb2,
                   const float* __restrict__ nW3,
                   const float* __restrict__ nb3,
                   const float* __restrict__ lW,
                   const float* __restrict__ lb,
                   const int* __restrict__ Rs,
                   const int* __restrict__ Rr,
                   float* __restrict__ out)
{
    __shared__ SM sm;
    const int t   = threadIdx.x;
    const int blk = blockIdx.x;       // 0..B_*N_-1
    const int b   = blk >> 12;
    const int n   = blk & (N_ - 1);
    const float HALF = 3.0f, BOXF = 6.0f;

    // ---- stage edge-MLP weights into LDS (zero-padded) ----
    for (int idx = t; idx < 152 * 160; idx += 256) {
        int r = idx / 160, c = idx - r * 160;
        sm.W2[r][c] = (r < ED && c < ED) ? eW2[r * ED + c] : 0.0f;
    }
    for (int idx = t; idx < EIN * 152; idx += 256) {
        int r = idx / 152, c = idx - r * 152;
        sm.W1[r][c] = (c < ED) ? eW1[r * ED + c] : 0.0f;
    }
    for (int j = t; j < 152; j += 256) {
        sm.b1[j] = (j < ED) ? eb1[j] : 0.0f;
        sm.b2[j] = (j < ED) ? eb2[j] : 0.0f;
    }

    const float dtv = dt[b];

    // ---- phase A (wave 0): detect int32 vs int64 indices, build 64 edge inputs ----
    if (t < EPN) {
        // If R_* is int64 (values < 4096, non-negative), every odd int32 word is 0.
        int wS = Rs[2 * t + 1];
        int wR = Rr[2 * t + 1];
        const bool i64S = (__ballot(wS == 0) == ~0ull);
        const bool i64R = (__ballot(wR == 0) == ~0ull);

        const int ebase = b * E_ + n * EPN + t;
        const int s = i64S ? Rs[2 * ebase] : Rs[ebase];
        const int r = i64R ? Rr[2 * ebase] : Rr[ebase];
        const float* vs = V + (b * N_ + s) * F_;
        const float* vr = V + (b * N_ + r) * F_;
        float s0 = vs[0], s1 = vs[1], s2 = vs[2], s3 = vs[3], s4 = vs[4];
        float r0 = vr[0], r1 = vr[1], r2 = vr[2], r3 = vr[3], r4 = vr[4];
        float d0 = s1 - r1, d1 = s2 - r2;
        d0 = (d0 >  HALF) ? d0 - BOXF : d0;
        d0 = (d0 <= -HALF) ? d0 + BOXF : d0;
        d1 = (d1 >  HALF) ? d1 - BOXF : d1;
        d1 = (d1 <= -HALF) ? d1 + BOXF : d1;
        sm.Ein[t][0] = s0; sm.Ein[t][1] = s3; sm.Ein[t][2] = s4;
        sm.Ein[t][3] = r0; sm.Ein[t][4] = r3; sm.Ein[t][5] = r4;
        sm.Ein[t][6] = d0; sm.Ein[t][7] = d1; sm.Ein[t][8] = dtv;
    }
    __syncthreads();

    const int g  = t & 7;             // column group
    const int e2 = t >> 3;            // 0..31 (pair of edges)
    const int e0 = e2 * 2, e1 = e0 + 1;

    // ---- phase B: h = relu(Ein @ W1 + b1) -> LDS ----
    {
        float ein0[EIN], ein1[EIN];
        #pragma unroll
        for (int k = 0; k < EIN; k++) { ein0[k] = sm.Ein[e0][k]; ein1[k] = sm.Ein[e1][k]; }
        #pragma unroll
        for (int i = 0; i < 19; i++) {
            int j = g + 8 * i;        // covers 0..151 (pad cols produce 0)
            float a0 = sm.b1[j], a1 = a0;
            #pragma unroll
            for (int k = 0; k < EIN; k++) {
                float w = sm.W1[k][j];
                a0 += ein0[k] * w;
                a1 += ein1[k] * w;
            }
            sm.h[e0][j] = fmaxf(a0, 0.0f);
            sm.h[e1][j] = fmaxf(a1, 0.0f);
        }
    }
    __syncthreads();

    // ---- phase C: En = relu(h @ W2 + b2); agg over 64 edges ----
    {
        // thread owns 5 float4 column-chunks: cols 4*(g+8u), u=0..4
        int c4[5];
        #pragma unroll
        for (int u = 0; u < 5; u++) c4[u] = 4 * (g + 8 * u);   // 0..156

        f4 acc0[5], acc1[5];
        #pragma unroll
        for (int u = 0; u < 5; u++) {
            if (c4[u] < 152) {
                f4 bb = *(const f4*)&sm.b2[c4[u]];
                acc0[u] = bb; acc1[u] = bb;
            } else {
                acc0[u] = (f4)0.0f; acc1[u] = (f4)0.0f;
            }
        }

        for (int k0 = 0; k0 < 152; k0 += 4) {
            f4 ha = *(const f4*)&sm.h[e0][k0];
            f4 hb = *(const f4*)&sm.h[e1][k0];
            #pragma unroll
            for (int kk = 0; kk < 4; kk++) {
                const float hak = ha[kk], hbk = hb[kk];
                const float* wrow = &sm.W2[k0 + kk][0];
                #pragma unroll
                for (int u = 0; u < 5; u++) {
                    f4 w = *(const f4*)&wrow[c4[u]];   // cols up to 159 exist (zero pad)
                    acc0[u] += hak * w;
                    acc1[u] += hbk * w;
                }
            }
        }

        const int wave = t >> 6;
        #pragma unroll
        for (int u = 0; u < 5; u++) {
            f4 s;
            #pragma unroll
            for (int j = 0; j < 4; j++)
                s[j] = fmaxf(acc0[u][j], 0.0f) + fmaxf(acc1[u][j], 0.0f);
            #pragma unroll
            for (int j = 0; j < 4; j++) {
                float v = s[j];
                v += __shfl_xor(v, 8);
                v += __shfl_xor(v, 16);
                v += __shfl_xor(v, 32);
                s[j] = v;
            }
            if (((t & 63) < 8) && c4[u] < 152)
                *(f4*)&sm.red[wave][c4[u]] = s;       // sum of this wave's 16 edges
        }
    }
    __syncthreads();

    // ---- finish agg, build node-MLP input ----
    if (t < ED) sm.nin[3 + t] = sm.red[0][t] + sm.red[1][t] + sm.red[2][t] + sm.red[3][t];
    if (t == 0) {
        const float* vn = V + (b * N_ + n) * F_;
        sm.nin[0] = vn[0]; sm.nin[1] = vn[3]; sm.nin[2] = vn[4];
        sm.nin[NIN - 1] = dtv;
    }
    __syncthreads();

    // ---- node MLP: 154 -> 100 -> 100 -> 100 (weights streamed, L2-resident) ----
    if (t < ND) {
        float a = nb1[t];
        for (int k = 0; k < NIN; k++) a += sm.nin[k] * nW1[k * ND + t];
        sm.hA[t] = fmaxf(a, 0.0f);
    }
    __syncthreads();
    if (t < ND) {
        float a = nb2[t];
        for (int k = 0; k < ND; k++) a += sm.hA[k] * nW2[k * ND + t];
        sm.hB[t] = fmaxf(a, 0.0f);
    }
    __syncthreads();
    if (t < ND) {
        float a = nb3[t];
        for (int k = 0; k < ND; k++) a += sm.hB[k] * nW3[k * ND + t];
        sm.hC[t] = fmaxf(a, 0.0f);
    }
    __syncthreads();

    // ---- linear head + residual + periodic wrap ----
    if (t < 4) {
        float a = lb[t];
        for (int k = 0; k < ND; k++) a += sm.hC[k] * lW[k * 4 + t];
        const float* vn = V + (b * N_ + n) * F_;
        float nv = vn[1 + t] + a;
        if (t < 2) {
            nv = (nv >=  HALF) ? nv - BOXF : nv;
            nv = (nv <  -HALF) ? nv + BOXF : nv;
        }
        out[(b * N_ + n) * 4 + t] = nv;
    }
}

extern "C" void kernel_launch(void* const* d_in, const int* in_sizes, int n_in,
                              void* d_out, int out_size, void* d_ws, size_t ws_size,
                              hipStream_t stream) {
    (void)in_sizes; (void)n_in; (void)d_ws; (void)ws_size; (void)out_size;
    const float* V   = (const float*)d_in[0];
    const float* dt  = (const float*)d_in[1];
    const float* eW1 = (const float*)d_in[2];
    const float* eb1 = (const float*)d_in[3];
    const float* eW2 = (const float*)d_in[4];
    const float* eb2 = (const float*)d_in[5];
    const float* nW1 = (const float*)d_in[6];
    const float* nb1 = (const float*)d_in[7];
    const float* nW2 = (const float*)d_in[8];
    const float* nb2 = (const float*)d_in[9];
    const float* nW3 = (const float*)d_in[10];
    const float* nb3 = (const float*)d_in[11];
    const float* lW  = (const float*)d_in[12];
    const float* lb  = (const float*)d_in[13];
    const int* Rs = (const int*)d_in[14];
    const int* Rr = (const int*)d_in[15];
    float* out = (float*)d_out;

    deltagn_fused<<<dim3(B_ * N_), dim3(256), 0, stream>>>(
        V, dt, eW1, eb1, eW2, eb2, nW1, nb1, nW2, nb2, nW3, nb3, lW, lb, Rs, Rr, out);
}

// Round 3
// 271.166 us; speedup vs baseline: 4.2912x; 4.2912x over previous
//
#include <hip/hip_runtime.h>

#define B_    2
#define N_    4096
#define E_    262144
#define F_    5
#define ED    150
#define ND    100
#define NIN   154
#define EIN   9
#define GN    16          // nodes per block
#define HSTR  168         // padded k-stride (bf16 elems): 336 B rows, 16B-aligned, bank-uniform

typedef __attribute__((ext_vector_type(8)))  short bf16x8;
typedef __attribute__((ext_vector_type(16))) float f32x16;

static __device__ __forceinline__ unsigned short f2bf(float x) {
    unsigned int u = __float_as_uint(x);
    unsigned int r = (u + 0x7fffu + ((u >> 16) & 1u)) >> 16;
    return (unsigned short)r;
}
static __device__ __forceinline__ float bf2f(unsigned short s) {
    return __uint_as_float(((unsigned int)s) << 16);
}
// swap bits 2<->3 of k: storage position so a lane's 8 frag elems are contiguous (one b128)
static __device__ __forceinline__ int kperm(int k) {
    return (k & ~12) | ((k & 4) << 1) | ((k & 8) >> 1);
}

__global__ __launch_bounds__(512, 2)
void deltagn_mfma(const float* __restrict__ V,  const float* __restrict__ dt,
                  const float* __restrict__ eW1, const float* __restrict__ eb1,
                  const float* __restrict__ eW2, const float* __restrict__ eb2,
                  const float* __restrict__ nW1, const float* __restrict__ nb1,
                  const float* __restrict__ nW2, const float* __restrict__ nb2,
                  const float* __restrict__ nW3, const float* __restrict__ nb3,
                  const float* __restrict__ lW,  const float* __restrict__ lb,
                  const int* __restrict__ Rs,   const int* __restrict__ Rr,
                  float* __restrict__ out)
{
    __shared__ struct __align__(16) {
        unsigned short w_hi[160][HSTR];   // W2^T split-hi, [n][kperm]
        unsigned short w_lo[160][HSTR];
        unsigned short h_hi[64][HSTR];    // layer-1 output split, [edge][kperm]
        unsigned short h_lo[64][HSTR];
        float nin[2][156];                // node-MLP input, double-buffered
        float hA[104], hB[104], hC[104];
    } sm;

    const int t    = threadIdx.x;
    const int wave = t >> 6;
    const int lane = t & 63;
    const int blk  = blockIdx.x;
    const int b    = blk >> 8;            // 256 blocks per batch
    const int n0   = (blk & 255) * GN;
    const float HALF = 3.0f, BOXF = 6.0f;

    // int64-vs-int32 index detection (values < 4096 => odd words all zero iff int64)
    const bool i64S = (__ballot(Rs[2*lane+1] == 0) == ~0ull);
    const bool i64R = (__ballot(Rr[2*lane+1] == 0) == ~0ull);

    // ---- stage W2^T (split bf16 hi/lo, k-permuted) into LDS ----
    {
        int4 z = {0,0,0,0};
        int4* pz = (int4*)&sm.w_hi[0][0];          // w_hi + w_lo are contiguous
        for (int i = t; i < (2*160*HSTR*2)/16; i += 512) pz[i] = z;
    }
    __syncthreads();
    for (int i = t; i < ED*ED; i += 512) {
        int k = i / ED, n = i - k*ED;              // eW2 is [k][n]
        float w = eW2[i];
        unsigned short hi = f2bf(w);
        unsigned short lo = f2bf(w - bf2f(hi));
        int kp = kperm(k);
        sm.w_hi[n][kp] = hi;
        sm.w_lo[n][kp] = lo;
    }
    __syncthreads();

    // ---- B fragments held in registers across ALL nodes (waves 0-4, wave = n-tile) ----
    bf16x8 bh[10], bl[10];
    float  b2v = 0.0f;
    if (wave < 5) {
        const int col  = wave*32 + (lane & 31);
        const int eoff = (lane >> 5) * 8;
        #pragma unroll
        for (int s = 0; s < 10; ++s) {
            bh[s] = *(const bf16x8*)&sm.w_hi[col][s*16 + eoff];
            bl[s] = *(const bf16x8*)&sm.w_lo[col][s*16 + eoff];
        }
        b2v = (col < ED) ? eb2[col] : 0.0f;
    }
    const float dtv = dt[b];

    // phase-B worker: one 16-col k-step (VALU fp32, scalar-broadcast W1), split+pack to LDS
    auto phaseB = [&](const float (&ein)[EIN], int kstep) {
        const int sb = __builtin_amdgcn_readfirstlane(kstep * 16);
        float hv[16];
        #pragma unroll
        for (int r = 0; r < 16; ++r) {
            const int c = sb + r;
            float a = 0.0f;
            if (c < ED) {
                a = eb1[c];
                #pragma unroll
                for (int q = 0; q < EIN; ++q) a += ein[q] * eW1[q*ED + c];
                a = fmaxf(a, 0.0f);
            }
            hv[r] = a;
        }
        constexpr int rm0[8] = {0,1,2,3,8,9,10,11};
        constexpr int rm1[8] = {4,5,6,7,12,13,14,15};
        bf16x8 h0, h1, l0, l1;
        #pragma unroll
        for (int e = 0; e < 8; ++e) {
            float x0 = hv[rm0[e]], x1 = hv[rm1[e]];
            unsigned short a0 = f2bf(x0), a1 = f2bf(x1);
            h0[e] = (short)a0;  l0[e] = (short)f2bf(x0 - bf2f(a0));
            h1[e] = (short)a1;  l1[e] = (short)f2bf(x1 - bf2f(a1));
        }
        *(bf16x8*)&sm.h_hi[lane][sb + 0] = h0;
        *(bf16x8*)&sm.h_hi[lane][sb + 8] = h1;
        *(bf16x8*)&sm.h_lo[lane][sb + 0] = l0;
        *(bf16x8*)&sm.h_lo[lane][sb + 8] = l1;
    };

    for (int g = 0; g <= GN + 1; ++g) {
        float ein[EIN];
        // ======== S1: Ein gather + phase-B half 1 | MLP-L1(g-1) | head(g-2) ========
        if (wave < 5 && g < GN) {
            const int ebase = b*E_ + (n0 + g)*64 + lane;
            const int si = i64S ? Rs[2*ebase] : Rs[ebase];
            const int ri = i64R ? Rr[2*ebase] : Rr[ebase];
            const float* vs = V + (b*N_ + si)*F_;
            const float* vr = V + (b*N_ + ri)*F_;
            float d0 = vs[1] - vr[1], d1 = vs[2] - vr[2];
            d0 = (d0 >  HALF) ? d0 - BOXF : d0;
            d0 = (d0 <= -HALF) ? d0 + BOXF : d0;
            d1 = (d1 >  HALF) ? d1 - BOXF : d1;
            d1 = (d1 <= -HALF) ? d1 + BOXF : d1;
            ein[0] = vs[0]; ein[1] = vs[3]; ein[2] = vs[4];
            ein[3] = vr[0]; ein[4] = vr[3]; ein[5] = vr[4];
            ein[6] = d0;    ein[7] = d1;    ein[8] = dtv;
            phaseB(ein, wave);
        }
        if ((wave == 5 || wave == 6) && g >= 1 && g <= GN) {
            const int j = (wave == 5) ? lane : 64 + lane;
            if (j < ND) {
                float a = nb1[j];
                const float* ninp = sm.nin[(g-1) & 1];
                #pragma unroll 7
                for (int k = 0; k < NIN; ++k) a += ninp[k] * nW1[k*ND + j];
                sm.hA[j] = fmaxf(a, 0.0f);
            }
        }
        if (wave == 7 && g >= 2 && lane < 4) {
            const int bn = b*N_ + n0 + (g - 2);
            float a = lb[lane];
            #pragma unroll 5
            for (int k = 0; k < ND; ++k) a += sm.hC[k] * lW[k*4 + lane];
            float nv = V[bn*F_ + 1 + lane] + a;
            if (lane < 2) {
                nv = (nv >=  HALF) ? nv - BOXF : nv;
                nv = (nv <  -HALF) ? nv + BOXF : nv;
            }
            out[bn*4 + lane] = nv;
        }
        __syncthreads();
        // ======== S2: phase-B half 2 | MLP-L2(g-1) ========
        if (wave < 5 && g < GN) phaseB(ein, wave + 5);
        if ((wave == 5 || wave == 6) && g >= 1 && g <= GN) {
            const int j = (wave == 5) ? lane : 64 + lane;
            if (j < ND) {
                float a = nb2[j];
                #pragma unroll 10
                for (int k = 0; k < ND; ++k) a += sm.hA[k] * nW2[k*ND + j];
                sm.hB[j] = fmaxf(a, 0.0f);
            }
        }
        __syncthreads();
        // ======== S3: MFMA edge GEMM + agg(g) | MLP-L3(g-1) | nin extras(g) ========
        if (wave < 5 && g < GN) {
            const int row  = lane & 31;
            const int eoff = (lane >> 5) * 8;
            f32x16 C0, C1;
            #pragma unroll
            for (int r = 0; r < 16; ++r) { C0[r] = 0.0f; C1[r] = 0.0f; }
            #pragma unroll
            for (int s = 0; s < 10; ++s) {
                bf16x8 ah0 = *(const bf16x8*)&sm.h_hi[row     ][s*16 + eoff];
                bf16x8 al0 = *(const bf16x8*)&sm.h_lo[row     ][s*16 + eoff];
                bf16x8 ah1 = *(const bf16x8*)&sm.h_hi[row + 32][s*16 + eoff];
                bf16x8 al1 = *(const bf16x8*)&sm.h_lo[row + 32][s*16 + eoff];
                C0 = __builtin_amdgcn_mfma_f32_32x32x16_bf16(ah0, bh[s], C0, 0, 0, 0);
                C1 = __builtin_amdgcn_mfma_f32_32x32x16_bf16(ah1, bh[s], C1, 0, 0, 0);
                C0 = __builtin_amdgcn_mfma_f32_32x32x16_bf16(ah0, bl[s], C0, 0, 0, 0);
                C1 = __builtin_amdgcn_mfma_f32_32x32x16_bf16(ah1, bl[s], C1, 0, 0, 0);
                C0 = __builtin_amdgcn_mfma_f32_32x32x16_bf16(al0, bh[s], C0, 0, 0, 0);
                C1 = __builtin_amdgcn_mfma_f32_32x32x16_bf16(al1, bh[s], C1, 0, 0, 0);
            }
            float colsum = 0.0f;
            #pragma unroll
            for (int r = 0; r < 16; ++r)
                colsum += fmaxf(C0[r] + b2v, 0.0f) + fmaxf(C1[r] + b2v, 0.0f);
            colsum += __shfl_xor(colsum, 32);
            if ((lane & 32) == 0) {
                const int col = wave*32 + lane;
                if (col < ED) sm.nin[g & 1][3 + col] = colsum;
            }
        }
        if (wave == 7 && g < GN) {
            const int bn = b*N_ + n0 + g;
            if (lane == 0) sm.nin[g & 1][0]   = V[bn*F_ + 0];
            if (lane == 1) sm.nin[g & 1][1]   = V[bn*F_ + 3];
            if (lane == 2) sm.nin[g & 1][2]   = V[bn*F_ + 4];
            if (lane == 3) sm.nin[g & 1][153] = dtv;
        }
        if ((wave == 5 || wave == 6) && g >= 1 && g <= GN) {
            const int j = (wave == 5) ? lane : 64 + lane;
            if (j < ND) {
                float a = nb3[j];
                #pragma unroll 10
                for (int k = 0; k < ND; ++k) a += sm.hB[k] * nW3[k*ND + j];
                sm.hC[j] = fmaxf(a, 0.0f);
            }
        }
        __syncthreads();
    }
}

extern "C" void kernel_launch(void* const* d_in, const int* in_sizes, int n_in,
                              void* d_out, int out_size, void* d_ws, size_t ws_size,
                              hipStream_t stream) {
    (void)in_sizes; (void)n_in; (void)d_ws; (void)ws_size; (void)out_size;
    const float* V   = (const float*)d_in[0];
    const float* dt  = (const float*)d_in[1];
    const float* eW1 = (const float*)d_in[2];
    const float* eb1 = (const float*)d_in[3];
    const float* eW2 = (const float*)d_in[4];
    const float* eb2 = (const float*)d_in[5];
    const float* nW1 = (const float*)d_in[6];
    const float* nb1 = (const float*)d_in[7];
    const float* nW2 = (const float*)d_in[8];
    const float* nb2 = (const float*)d_in[9];
    const float* nW3 = (const float*)d_in[10];
    const float* nb3 = (const float*)d_in[11];
    const float* lW  = (const float*)d_in[12];
    const float* lb  = (const float*)d_in[13];
    const int* Rs = (const int*)d_in[14];
    const int* Rr = (const int*)d_in[15];
    float* out = (float*)d_out;

    deltagn_mfma<<<dim3(512), dim3(512), 0, stream>>>(
        V, dt, eW1, eb1, eW2, eb2, nW1, nb1, nW2, nb2, nW3, nb3, lW, lb, Rs, Rr, out);
}